// Round 2
// baseline (157.722 us; speedup 1.0000x reference)
//
#include <hip/hip_runtime.h>

// ---------------- problem constants (fixed by setup_inputs) ----------------
constexpr int B_ = 2, N_ = 8192, M_ = 8192, Dd = 64;
constexpr int TN = 128;            // rows (n) per block
constexpr int TM = 128;            // ref rows (m) per chunk
constexpr int SPLIT = 8;           // M-splits; = XCD count, blockIdx&7 pins split->XCD
constexpr int MCHUNK = M_ / SPLIT; // 1024
constexpr int NCHUNKS = MCHUNK / TM; // 8
constexpr int NT = N_ / TN;        // 64 n-tiles
constexpr float LOG2E   = 1.4426950408889634f;
constexpr float SCALE_S = LOG2E / 64.0f;    //  dot/64   in log2 domain
constexpr float SCALE_N = -LOG2E / 128.0f;  // -|v|^2/128 in log2 domain

// Guide-verified MFMA operand types (learn_hip m89/m91): 8 bf16 carried as short8.
using s16x8 = __attribute__((ext_vector_type(8))) short;
using f32x4 = __attribute__((ext_vector_type(4))) float;

#if defined(__has_builtin)
#if __has_builtin(__builtin_amdgcn_exp2f)
#define EXP2(x) __builtin_amdgcn_exp2f(x)
#endif
#endif
#ifndef EXP2
#define EXP2(x) exp2f(x)
#endif

__device__ __forceinline__ unsigned short f2bf(float f) {
  unsigned u = __builtin_bit_cast(unsigned, f);
  u += 0x7FFFu + ((u >> 16) & 1u);   // round-to-nearest-even (values finite)
  return (unsigned short)(u >> 16);
}

__device__ __forceinline__ f32x4 mfma16(s16x8 a, s16x8 b, f32x4 c) {
  return __builtin_amdgcn_mfma_f32_16x16x32_bf16(a, b, c, 0, 0, 0);
}

// A/B frag (16x16x32): outer index = lane&15, 8 k-contiguous bf16 at k0=(lane>>4)*8.
// C/D: col = lane&15, row = (lane>>4)*4 + reg.   [measured m89/m91]

__global__ __launch_bounds__(256, 2) void msflash_kernel(
    const float* __restrict__ pts, const float* __restrict__ ref,
    float* __restrict__ num_acc, float* __restrict__ den_acc) {
  // LDS strides: 72 shorts = 144 B, 136 shorts = 272 B -> 16B-aligned, non-128B-multiple
  __shared__ unsigned short ldsY [TM][72];   // Y chunk [m][d]   (QK B-frags)  18432 B
  __shared__ unsigned short ldsYT[Dd][136];  // Y chunk [d][m]   (PV B-frags)  17408 B
  __shared__ unsigned short ldsP [4][32][72];// per-wave P half  [n][m0..63]   18432 B
  __shared__ float lds_an2[TN];
  __shared__ float lds_bm2[TM];

  const int tid  = threadIdx.x;
  const int w    = tid >> 6;
  const int lane = tid & 63;
  const int l15  = lane & 15, quad = lane >> 4;

  const int s  = blockIdx.x & (SPLIT - 1);
  const int r  = blockIdx.x >> 3;
  const int bb = r / NT;
  const int nt = r % NT;
  const int n0 = nt * TN;
  const int m_begin = s * MCHUNK;

  // ---- stage X (fp32 -> bf16) into ldsP region (alias, pre-loop only) + row norms ----
  unsigned short (*ldsX)[72] = (unsigned short (*)[72]) & ldsP[0][0][0]; // 128x72 alias
  {
    const int rowl = tid >> 1, half = tid & 1;
    const float* gp = pts + ((size_t)bb * N_ + n0 + rowl) * Dd + half * 32;
    float4 f[8];
#pragma unroll
    for (int i = 0; i < 8; i++) f[i] = ((const float4*)gp)[i];
    float sq = 0.f;
#pragma unroll
    for (int i = 0; i < 8; i++)
      sq += f[i].x * f[i].x + f[i].y * f[i].y + f[i].z * f[i].z + f[i].w * f[i].w;
    sq += __shfl_xor(sq, 1);                 // combine the two half-rows
    if (half == 0) lds_an2[rowl] = sq * SCALE_N;
    unsigned short hv[32];
#pragma unroll
    for (int i = 0; i < 8; i++) {
      hv[4 * i + 0] = f2bf(f[i].x); hv[4 * i + 1] = f2bf(f[i].y);
      hv[4 * i + 2] = f2bf(f[i].z); hv[4 * i + 3] = f2bf(f[i].w);
    }
    uint4* dv = (uint4*)&ldsX[rowl][half * 32];
#pragma unroll
    for (int i = 0; i < 4; i++) {
      dv[i] = make_uint4(
        (unsigned)hv[8*i+0] | ((unsigned)hv[8*i+1] << 16),
        (unsigned)hv[8*i+2] | ((unsigned)hv[8*i+3] << 16),
        (unsigned)hv[8*i+4] | ((unsigned)hv[8*i+5] << 16),
        (unsigned)hv[8*i+6] | ((unsigned)hv[8*i+7] << 16));
    }
  }
  __syncthreads();

  // X A-frags + per-row norm terms live in registers for the whole kernel
  s16x8 ax[2][2];
  f32x4 anr[2];
#pragma unroll
  for (int rt = 0; rt < 2; rt++) {
#pragma unroll
    for (int ks = 0; ks < 2; ks++)
      ax[rt][ks] = *(const s16x8*)&ldsX[w * 32 + rt * 16 + l15][ks * 32 + quad * 8];
    anr[rt] = *(const f32x4*)&lds_an2[w * 32 + rt * 16 + quad * 4];
  }

  f32x4 o[2][4], den[2];
#pragma unroll
  for (int rt = 0; rt < 2; rt++) {
    den[rt] = f32x4{0.f, 0.f, 0.f, 0.f};
#pragma unroll
    for (int dt = 0; dt < 4; dt++) o[rt][dt] = f32x4{0.f, 0.f, 0.f, 0.f};
  }
  s16x8 ones;
#pragma unroll
  for (int j = 0; j < 8; j++) ones[j] = (l15 == 0) ? (short)0x3F80 : (short)0;

  for (int c = 0; c < NCHUNKS; c++) {
    __syncthreads();  // previous chunk's PV reads of ldsY/ldsYT done
    {   // ---- stage Y chunk: [m][d], [d][m] transpose, and -|y|^2/128 terms ----
      const int rowl = tid >> 1, half = tid & 1;
      const int mg = m_begin + c * TM + rowl;
      const float* gp = ref + ((size_t)bb * M_ + mg) * Dd + half * 32;
      float4 f[8];
#pragma unroll
      for (int i = 0; i < 8; i++) f[i] = ((const float4*)gp)[i];
      float sq = 0.f;
#pragma unroll
      for (int i = 0; i < 8; i++)
        sq += f[i].x * f[i].x + f[i].y * f[i].y + f[i].z * f[i].z + f[i].w * f[i].w;
      sq += __shfl_xor(sq, 1);
      if (half == 0) lds_bm2[rowl] = sq * SCALE_N;
      unsigned short hv[32];
#pragma unroll
      for (int i = 0; i < 8; i++) {
        hv[4 * i + 0] = f2bf(f[i].x); hv[4 * i + 1] = f2bf(f[i].y);
        hv[4 * i + 2] = f2bf(f[i].z); hv[4 * i + 3] = f2bf(f[i].w);
      }
      uint4* dv = (uint4*)&ldsY[rowl][half * 32];
#pragma unroll
      for (int i = 0; i < 4; i++) {
        dv[i] = make_uint4(
          (unsigned)hv[8*i+0] | ((unsigned)hv[8*i+1] << 16),
          (unsigned)hv[8*i+2] | ((unsigned)hv[8*i+3] << 16),
          (unsigned)hv[8*i+4] | ((unsigned)hv[8*i+5] << 16),
          (unsigned)hv[8*i+6] | ((unsigned)hv[8*i+7] << 16));
      }
#pragma unroll
      for (int j = 0; j < 32; j++) ldsYT[half * 32 + j][rowl] = hv[j];
    }
    __syncthreads();

#pragma unroll
    for (int h = 0; h < 2; h++) {   // 64-column halves of the S tile
      // ---- QK: S[32 x 64] per wave ----
      f32x4 sf[2][4];
#pragma unroll
      for (int ct = 0; ct < 4; ct++) {
        s16x8 by0 = *(const s16x8*)&ldsY[h * 64 + ct * 16 + l15][quad * 8];
        s16x8 by1 = *(const s16x8*)&ldsY[h * 64 + ct * 16 + l15][32 + quad * 8];
#pragma unroll
        for (int rt = 0; rt < 2; rt++) {
          f32x4 acc = f32x4{0.f, 0.f, 0.f, 0.f};
          acc = mfma16(ax[rt][0], by0, acc);
          acc = mfma16(ax[rt][1], by1, acc);
          sf[rt][ct] = acc;
        }
      }
      // ---- exp2 + write P (bf16) to wave-private LDS, [n][m] (A-layout source) ----
#pragma unroll
      for (int ct = 0; ct < 4; ct++) {
        float bm2v = lds_bm2[h * 64 + ct * 16 + l15];
#pragma unroll
        for (int rt = 0; rt < 2; rt++) {
          unsigned short* pb = &ldsP[w][rt * 16 + quad * 4][ct * 16 + l15];
#pragma unroll
          for (int g = 0; g < 4; g++) {
            float arg = sf[rt][ct][g] * SCALE_S + anr[rt][g] + bm2v;
            pb[(size_t)g * 72] = f2bf(EXP2(arg));
          }
        }
      }
      // ---- PV: O += P * Y, den += P * 1 (wave-private P; no barrier needed) ----
      s16x8 pf[2][2];
#pragma unroll
      for (int rt = 0; rt < 2; rt++)
#pragma unroll
        for (int ks = 0; ks < 2; ks++)
          pf[rt][ks] = *(const s16x8*)&ldsP[w][rt * 16 + l15][ks * 32 + quad * 8];
#pragma unroll
      for (int dt = 0; dt < 4; dt++) {
        s16x8 bv0 = *(const s16x8*)&ldsYT[dt * 16 + l15][h * 64 + quad * 8];
        s16x8 bv1 = *(const s16x8*)&ldsYT[dt * 16 + l15][h * 64 + 32 + quad * 8];
#pragma unroll
        for (int rt = 0; rt < 2; rt++) {
          o[rt][dt] = mfma16(pf[rt][0], bv0, o[rt][dt]);
          o[rt][dt] = mfma16(pf[rt][1], bv1, o[rt][dt]);
        }
      }
#pragma unroll
      for (int rt = 0; rt < 2; rt++) {
        den[rt] = mfma16(pf[rt][0], ones, den[rt]);
        den[rt] = mfma16(pf[rt][1], ones, den[rt]);
      }
    }
  }

  // ---- epilogue: fp32 atomic partials ----
  float* nb = num_acc + ((size_t)bb * N_ + n0) * Dd;
#pragma unroll
  for (int rt = 0; rt < 2; rt++) {
    const int row0 = w * 32 + rt * 16 + quad * 4;
#pragma unroll
    for (int dt = 0; dt < 4; dt++) {
      const int col = dt * 16 + l15;
#pragma unroll
      for (int g = 0; g < 4; g++)
        atomicAdd(&nb[(size_t)(row0 + g) * Dd + col], o[rt][dt][g]);
    }
    if (l15 == 0) {
#pragma unroll
      for (int g = 0; g < 4; g++)
        atomicAdd(&den_acc[(size_t)bb * N_ + n0 + row0 + g], den[rt][g]);
    }
  }
}

__global__ __launch_bounds__(256) void msdiv_kernel(
    const float* __restrict__ num, const float* __restrict__ den,
    float* __restrict__ out) {
  const int i = blockIdx.x * 256 + threadIdx.x;  // float4 index; grid covers exactly
  float4 v = ((const float4*)num)[i];
  const float inv = 1.0f / den[i >> 4];          // 16 float4 per 64-wide row
  ((float4*)out)[i] = make_float4(v.x * inv, v.y * inv, v.z * inv, v.w * inv);
}

extern "C" void kernel_launch(void* const* d_in, const int* in_sizes, int n_in,
                              void* d_out, int out_size, void* d_ws, size_t ws_size,
                              hipStream_t stream) {
  const float* pts = (const float*)d_in[0];
  const float* ref = (const float*)d_in[1];
  float* out = (float*)d_out;
  float* num = (float*)d_ws;                       // [B,N,64] fp32 partial numerators
  float* den = num + (size_t)B_ * N_ * Dd;         // [B,N]    fp32 partial denominators
  const size_t acc_bytes = ((size_t)B_ * N_ * Dd + (size_t)B_ * N_) * sizeof(float);

  hipMemsetAsync(d_ws, 0, acc_bytes, stream);      // ws is re-poisoned 0xAA each launch
  msflash_kernel<<<dim3(B_ * NT * SPLIT), dim3(256), 0, stream>>>(pts, ref, num, den);
  const int tot4 = B_ * N_ * Dd / 4;               // 262144
  msdiv_kernel<<<dim3(tot4 / 256), dim3(256), 0, stream>>>(num, den, out);
}